// Round 3
// baseline (2981.882 us; speedup 1.0000x reference)
//
#include <hip/hip_runtime.h>
#include <math.h>

// Conv1D(k=2,F=64,relu) -> LSTM1(H=100, relu cell, seq) -> LSTM2 (last) ->
// Dense(3) -> softmax.  B=128, T=2048, T'=2047.
//
// Round-8 design: kill the register-overflow overhead.
//  Diagnosis: rounds 5-7 all report VGPR_Count=128 while each dot-thread
//  holds 176-200 h2 weights -> weights lived in AGPR/scratch (WRITE_SIZE
//  15-46 MB of spill traffic, v_accvgpr/reload ops ~double the VALU stream;
//  active-CU VALUBusy ~75% => issue-bound on overhead).
//  Fix: 1024-thread block (16 waves, 4 waves/SIMD, 128-VGPR cap = exactly
//  the 2048-reg CU file), and DOUBLE both dot pools so weights/thread fit
//  in arch VGPRs:
//   * producer 400 thr: (unit p, K-quarter s) over K1=192 [x64;h100;pad28]
//     (round-6 proven layout): 24 h2 x 4 gates = 96 h2/thread.  qsum4 quad
//     reduction (DPP 0xB1+0x4E, proven round 6/7).
//   * consumer 400 thr: (unit p, gate-pair g2, K-half kh) over K2=208
//     [x2 100;pad4;h2 100;pad4]: 52 h2 x 2 gates = 104 h2/thread.
//     psum2 over kh (xor-1 DPP), then one xor-2 DPP exchange of the two
//     gate-pair z's within the quad -> each lane has all 4 gates, computes
//     the cell redundantly (bitwise identical), lane (rt&3)==0 writes h.
//   * conv on its own wave (64 thr, 1 filter each) feeding the X1 ring.
//  Ring/slot schedule identical to round-5 (1 barrier/step; producer one
//  step ahead of consumer through 2-slot LDS rings).

typedef _Float16 h2 __attribute__((ext_vector_type(2)));

#define BB 128
#define TT 2048
#define TP 2047
#define HH 100
#define G4 400
#define FF 64

#define K1 192   // producer combined-K halves: [x(64) ; h1(100) ; pad(28)]
#define K2 208   // consumer combined-K halves: [x2(100); pad4 ; h2(100); pad4]

#define L24(X) X(0) X(1) X(2) X(3) X(4) X(5) X(6) X(7) X(8) X(9) \
 X(10) X(11) X(12) X(13) X(14) X(15) X(16) X(17) X(18) X(19) \
 X(20) X(21) X(22) X(23)
#define L52(X) L24(X) X(24) X(25) X(26) X(27) X(28) X(29) \
 X(30) X(31) X(32) X(33) X(34) X(35) X(36) X(37) X(38) X(39) \
 X(40) X(41) X(42) X(43) X(44) X(45) X(46) X(47) X(48) X(49) \
 X(50) X(51)

// ---------------- producer weight machinery (96 h2 / thread) ---------------
#define PDW(i) h2 pa##i, pb##i, pc##i, pd##i;

// producer combined column: K = [conv-x(64) ; U(100) ; pad(28)] -> 192
static __device__ __forceinline__ _Float16 pw(const float* __restrict__ W,
                                              const float* __restrict__ U,
                                              int c, int k) {
    float v = (k < FF) ? W[k * G4 + c] : (k < FF + HH ? U[(k - FF) * G4 + c] : 0.0f);
    return (_Float16)v;
}

#define LWP(i) { const int k = kb + 2 * (i); \
  pa##i = h2{pw(W,U,cA,k), pw(W,U,cA,k+1)}; \
  pb##i = h2{pw(W,U,cB,k), pw(W,U,cB,k+1)}; \
  pc##i = h2{pw(W,U,cC,k), pw(W,U,cC,k+1)}; \
  pd##i = h2{pw(W,U,cD,k), pw(W,U,cD,k+1)}; }

// ---------------- consumer weight machinery (104 h2 / thread) --------------
#define CDW(i) h2 ca##i, cb##i;

// consumer combined column: K = [W2(100) ; pad(4) ; U2(100) ; pad(4)] -> 208
static __device__ __forceinline__ _Float16 cw(const float* __restrict__ W,
                                              const float* __restrict__ U,
                                              int c, int k) {
    float v = (k < HH) ? W[k * G4 + c]
            : (k < 104 ? 0.0f : (k < 204 ? U[(k - 104) * G4 + c] : 0.0f));
    return (_Float16)v;
}

#define LWC(i) { const int k = kb + 2 * (i); \
  ca##i = h2{cw(W,U,cL,k), cw(W,U,cL,k+1)}; \
  cb##i = h2{cw(W,U,cH,k), cw(W,U,cH,k+1)}; }

// ---------------- dot kernels ----------------------------------------------
#define FD(w, x, acc) acc = __builtin_amdgcn_fdot2(w, x, acc, false)
#define B2(f) __builtin_bit_cast(h2, f)

// producer: one float4 chunk feeds 4 gates (8 chains via element parity)
#define DOTP(r, i0, i1, i2, i3) { const float4 v = vb[r]; \
  const h2 x0 = B2(v.x), x1 = B2(v.y), x2 = B2(v.z), x3 = B2(v.w); \
  FD(pa##i0, x0, zA0); FD(pb##i0, x0, zB0); FD(pc##i0, x0, zC0); FD(pd##i0, x0, zD0); \
  FD(pa##i1, x1, zA1); FD(pb##i1, x1, zB1); FD(pc##i1, x1, zC1); FD(pd##i1, x1, zD1); \
  FD(pa##i2, x2, zA0); FD(pb##i2, x2, zB0); FD(pc##i2, x2, zC0); FD(pd##i2, x2, zD0); \
  FD(pa##i3, x3, zA1); FD(pb##i3, x3, zB1); FD(pc##i3, x3, zC1); FD(pd##i3, x3, zD1); }

// consumer: one float4 chunk feeds 2 gates (4 chains via element parity)
#define DOTC(r, i0, i1, i2, i3) { const float4 v = vb[r]; \
  const h2 x0 = B2(v.x), x1 = B2(v.y), x2 = B2(v.z), x3 = B2(v.w); \
  FD(ca##i0, x0, zA0); FD(cb##i0, x0, zB0); \
  FD(ca##i1, x1, zA1); FD(cb##i1, x1, zB1); \
  FD(ca##i2, x2, zA0); FD(cb##i2, x2, zB0); \
  FD(ca##i3, x3, zA1); FD(cb##i3, x3, zB1); }

// ---------------- cross-lane primitives (DPP, pure VALU) --------------------
// 0xB1 = quad_perm [1,0,3,2] (xor 1), 0x4E = quad_perm [2,3,0,1] (xor 2)
static __device__ __forceinline__ float qsum4(float z) {
    int p1 = __builtin_amdgcn_update_dpp(0, __builtin_bit_cast(int, z),
                                         0xB1, 0xF, 0xF, true);
    float s1 = z + __builtin_bit_cast(float, p1);
    int p2 = __builtin_amdgcn_update_dpp(0, __builtin_bit_cast(int, s1),
                                         0x4E, 0xF, 0xF, true);
    return s1 + __builtin_bit_cast(float, p2);
}
static __device__ __forceinline__ float psum2(float z) {
    int p1 = __builtin_amdgcn_update_dpp(0, __builtin_bit_cast(int, z),
                                         0xB1, 0xF, 0xF, true);
    return z + __builtin_bit_cast(float, p1);
}
static __device__ __forceinline__ float xswap2(float z) {   // value from lane^2
    int p2 = __builtin_amdgcn_update_dpp(0, __builtin_bit_cast(int, z),
                                         0x4E, 0xF, 0xF, true);
    return __builtin_bit_cast(float, p2);
}
static __device__ __forceinline__ float sig(float z) {
    return 1.0f / (1.0f + __expf(-z));
}

__global__ __launch_bounds__(1024, 4)
void fused_lstm_kernel(const float* __restrict__ s,       // [B,T]
                       const float* __restrict__ conv_w,  // [2,1,F]
                       const float* __restrict__ conv_b,  // [F]
                       const float* __restrict__ w1, const float* __restrict__ u1,
                       const float* __restrict__ b1,
                       const float* __restrict__ w2, const float* __restrict__ u2,
                       const float* __restrict__ b2,
                       const float* __restrict__ dw, const float* __restrict__ db,
                       float* __restrict__ out)           // [B,3]
{
    const int tid = threadIdx.x;
    const int b   = blockIdx.x;

    __shared__ float s_buf[TT];                        // 8 KB input row
    __shared__ __align__(16) _Float16 X1[2 * K1];      // producer operand ring
    __shared__ __align__(16) _Float16 X2[2 * K2];      // consumer operand ring

    for (int i = tid; i < TT; i += 1024) s_buf[i] = s[(size_t)b * TT + i];
    if (tid < 2 * K1) X1[tid] = (_Float16)0.0f;        // pads stay 0 forever
    if (tid < 2 * K2) X2[tid] = (_Float16)0.0f;
    __syncthreads();                                   // (A)

    if (tid < 448) {
        // ============ PRODUCER: waves 0-6, 400 dot threads ============
        const int rt     = tid;
        const int active = (rt < 400);
        const int p      = active ? (rt >> 2) : 0;     // unit
        const int sq     = rt & 3;                     // K-quarter
        const int cA = p, cB = HH + p, cC = 2 * HH + p, cD = 3 * HH + p;
        const float* W = w1;
        const float* U = u1;
        const int kb = sq * 48;                        // quarter base (halves)

        L24(PDW)
        L24(LWP)
        const float bA = b1[cA], bB = b1[cB], bC = b1[cC], bD = b1[cD];
        __syncthreads();                               // (B)

        float c = 0.0f;
        for (int t = 0; t <= TP; ++t) {
            if (t < TP && active) {
                _Float16* cur = X1 + (t & 1) * K1;
                _Float16* nx1 = X1 + ((t & 1) ^ 1) * K1;
                _Float16* x2n = X2 + ((t & 1) ^ 1) * K2;
                float zA0 = 0.f, zA1 = 0.f, zB0 = 0.f, zB1 = 0.f;
                float zC0 = 0.f, zC1 = 0.f, zD0 = 0.f, zD1 = 0.f;
                const float4* vb = (const float4*)(cur + kb);
                DOTP(0, 0, 1, 2, 3)     DOTP(1, 4, 5, 6, 7)
                DOTP(2, 8, 9, 10, 11)   DOTP(3, 12, 13, 14, 15)
                DOTP(4, 16, 17, 18, 19) DOTP(5, 20, 21, 22, 23)
                const float zi = qsum4(zA0 + zA1) + bA;
                const float zf = qsum4(zB0 + zB1) + bB;
                const float zg = qsum4(zC0 + zC1) + bC;
                const float zo = qsum4(zD0 + zD1) + bD;
                c = fmaf(sig(zf), c, sig(zi) * fmaxf(zg, 0.f));
                const float h = sig(zo) * fmaxf(c, 0.f);
                if (sq == 0) {
                    const _Float16 hq = (_Float16)h;
                    nx1[FF + p] = hq;                  // h1 for LSTM1(t+1)
                    x2n[p]      = hq;                  // x2 for LSTM2
                }
            }
            __syncthreads();                           // (C)
        }
    } else if (tid < 896) {
        // ============ CONSUMER: waves 7-13, 400 dot threads ============
        const int rt     = tid - 448;
        const int active = (rt < 400);
        const int p      = active ? (rt >> 2) : 0;     // unit
        const int g2     = (rt >> 1) & 1;              // gate pair: 0->{i,f}, 1->{g,o}
        const int kh     = rt & 1;                     // K-half
        const int cL = (2 * g2) * HH + p;              // first gate col
        const int cH = cL + HH;                        // second gate col
        const float* W = w2;
        const float* U = u2;
        const int kb = kh * 104;                       // half base (halves)

        L52(CDW)
        L52(LWC)
        const float bL = b2[cL], bH = b2[cH];
        __syncthreads();                               // (B)

        float c = 0.0f;
        for (int t = 0; t <= TP; ++t) {
            if (t >= 1 && active) {                    // consumer step t-1
                _Float16* cur = X2 + (t & 1) * K2;
                float zA0 = 0.f, zA1 = 0.f, zB0 = 0.f, zB1 = 0.f;
                const float4* vb = (const float4*)(cur + kb);
                DOTC(0, 0, 1, 2, 3)      DOTC(1, 4, 5, 6, 7)
                DOTC(2, 8, 9, 10, 11)    DOTC(3, 12, 13, 14, 15)
                DOTC(4, 16, 17, 18, 19)  DOTC(5, 20, 21, 22, 23)
                DOTC(6, 24, 25, 26, 27)  DOTC(7, 28, 29, 30, 31)
                DOTC(8, 32, 33, 34, 35)  DOTC(9, 36, 37, 38, 39)
                DOTC(10, 40, 41, 42, 43) DOTC(11, 44, 45, 46, 47)
                DOTC(12, 48, 49, 50, 51)
                // sum K-halves (partner = lane^1, same p,g2)
                const float za = psum2(zA0 + zA1) + bL;
                const float zb = psum2(zB0 + zB1) + bH;
                // exchange gate pairs (partner = lane^2, same p,kh)
                const float oa = xswap2(za);
                const float ob = xswap2(zb);
                const float zi = g2 ? oa : za;
                const float zf = g2 ? ob : zb;
                const float zg = g2 ? za : oa;
                const float zo = g2 ? zb : ob;
                c = fmaf(sig(zf), c, sig(zi) * fmaxf(zg, 0.f));
                const float h = sig(zo) * fmaxf(c, 0.f);
                if ((rt & 3) == 0)
                    X2[((t & 1) ^ 1) * K2 + 104 + p] = (_Float16)h;
            }
            __syncthreads();                           // (C)
        }

        // final h2(TP-1) was written at iter TP into slot ((TP&1)^1)=0
        if (rt == 0) {
            float l[3];
#pragma unroll
            for (int a = 0; a < 3; ++a) {
                float acc = db[a];
                for (int j = 0; j < HH; ++j)
                    acc = fmaf((float)X2[104 + j], dw[j * 3 + a], acc);
                l[a] = acc;
            }
            const float m = fmaxf(l[0], fmaxf(l[1], l[2]));
            const float e0 = __expf(l[0] - m), e1 = __expf(l[1] - m), e2 = __expf(l[2] - m);
            const float inv = 1.0f / (e0 + e1 + e2);
            out[b * 3 + 0] = e0 * inv;
            out[b * 3 + 1] = e1 * inv;
            out[b * 3 + 2] = e2 * inv;
        }
    } else if (tid < 960) {
        // ============ CONV: wave 14, 64 threads (1 filter each) ============
        const int f = tid - 896;
        const float cv0 = conv_w[f], cv1 = conv_w[FF + f], cb0 = conv_b[f];
        // x(0) into slot 0
        X1[f] = (_Float16)fmaxf(fmaf(s_buf[0], cv0, fmaf(s_buf[1], cv1, cb0)), 0.f);
        __syncthreads();                               // (B)

        for (int t = 0; t <= TP; ++t) {
            if (t + 1 < TP) {                          // conv x(t+1) into next slot
                _Float16* nx1 = X1 + ((t & 1) ^ 1) * K1;
                nx1[f] = (_Float16)fmaxf(fmaf(s_buf[t + 1], cv0, fmaf(s_buf[t + 2], cv1, cb0)), 0.f);
            }
            __syncthreads();                           // (C)
        }
    } else {
        // ============ wave 15: barrier companion only ============
        __syncthreads();                               // (B)
        for (int t = 0; t <= TP; ++t)
            __syncthreads();                           // (C)
    }
}

// ---------------- launch ----------------------------------------------------
extern "C" void kernel_launch(void* const* d_in, const int* in_sizes, int n_in,
                              void* d_out, int out_size, void* d_ws, size_t ws_size,
                              hipStream_t stream) {
    const float* s      = (const float*)d_in[0];
    const float* conv_w = (const float*)d_in[1];
    const float* conv_b = (const float*)d_in[2];
    const float* w1     = (const float*)d_in[3];
    const float* u1     = (const float*)d_in[4];
    const float* b1     = (const float*)d_in[5];
    const float* w2     = (const float*)d_in[6];
    const float* u2     = (const float*)d_in[7];
    const float* b2     = (const float*)d_in[8];
    const float* dw     = (const float*)d_in[9];
    const float* db     = (const float*)d_in[10];

    fused_lstm_kernel<<<BB, 1024, 0, stream>>>(
        s, conv_w, conv_b, w1, u1, b1, w2, u2, b2, dw, db, (float*)d_out);
}

// Round 4
// 2931.079 us; speedup vs baseline: 1.0173x; 1.0173x over previous
//
#include <hip/hip_runtime.h>
#include <math.h>

// Conv1D(k=2,F=64,relu) -> LSTM1(H=100, relu cell, seq) -> LSTM2 (last) ->
// Dense(3) -> softmax.  B=128, T=2048, T'=2047.
//
// Round-9 = round-8 structure, spill actually fixed.
//  Post-mortem r8: VGPR_Count fell to 64 because __launch_bounds__'s 2nd arg
//  behaves like CUDA min-BLOCKS-per-CU: (1024,4) -> clamped 2 blocks/CU ->
//  8 waves/SIMD -> 64-VGPR cap -> ~40 regs/thread spilled (WRITE 37.6 MB).
//  Fix:
//   * __launch_bounds__(1024, 1): 1 block/CU, 16 waves = 4 waves/SIMD ->
//     128-VGPR cap (also the HW max for a 1024-thread block).
//   * consumer drops statically-dead pad weights: each K-half = 100 real +
//     4 pad halves, so weight pairs i=50,51 are ALWAYS pad -> 100 h2/thread
//     (~121 regs total); producer 96 h2 (~119 regs).  Both spill-free at 128.
//  Structure (verified correct in r8):
//   * producer 400 thr: (unit p, K-quarter sq) over K1=192 [x64;h1 100;pad28],
//     24 h2 x 4 gates; qsum4 quad reduction (DPP 0xB1 + 0x4E).
//   * consumer 400 thr: (unit p, gate-pair g2, K-half kh) over K2=208
//     [x2 100;pad4;h2 100;pad4]; 50 h2 x 2 gates; psum2 (xor-1) over kh then
//     xor-2 exchange of gate-pair z's; all 4 quad lanes compute the cell
//     redundantly; lane (rt&3)==0 writes h.
//   * conv wave (64 thr, 1 filter each) feeds the X1 ring; wave 15 barriers.
//   * 2-slot LDS rings, 1 barrier/step, producer 1 step ahead of consumer.

typedef _Float16 h2 __attribute__((ext_vector_type(2)));

#define BB 128
#define TT 2048
#define TP 2047
#define HH 100
#define G4 400
#define FF 64

#define K1 192   // producer combined-K halves: [x(64) ; h1(100) ; pad(28)]
#define K2 208   // consumer combined-K halves: [x2(100); pad4 ; h2(100); pad4]

#define L24(X) X(0) X(1) X(2) X(3) X(4) X(5) X(6) X(7) X(8) X(9) \
 X(10) X(11) X(12) X(13) X(14) X(15) X(16) X(17) X(18) X(19) \
 X(20) X(21) X(22) X(23)
#define L50(X) L24(X) X(24) X(25) X(26) X(27) X(28) X(29) \
 X(30) X(31) X(32) X(33) X(34) X(35) X(36) X(37) X(38) X(39) \
 X(40) X(41) X(42) X(43) X(44) X(45) X(46) X(47) X(48) X(49)

// ---------------- producer weight machinery (96 h2 / thread) ---------------
#define PDW(i) h2 pa##i, pb##i, pc##i, pd##i;

// producer combined column: K = [conv-x(64) ; U(100) ; pad(28)] -> 192
static __device__ __forceinline__ _Float16 pw(const float* __restrict__ W,
                                              const float* __restrict__ U,
                                              int c, int k) {
    float v = (k < FF) ? W[k * G4 + c] : (k < FF + HH ? U[(k - FF) * G4 + c] : 0.0f);
    return (_Float16)v;
}

#define LWP(i) { const int k = kb + 2 * (i); \
  pa##i = h2{pw(W,U,cA,k), pw(W,U,cA,k+1)}; \
  pb##i = h2{pw(W,U,cB,k), pw(W,U,cB,k+1)}; \
  pc##i = h2{pw(W,U,cC,k), pw(W,U,cC,k+1)}; \
  pd##i = h2{pw(W,U,cD,k), pw(W,U,cD,k+1)}; }

// ---------------- consumer weight machinery (100 h2 / thread) --------------
#define CDW(i) h2 ca##i, cb##i;

// consumer combined column: K = [W2(100) ; pad(4) ; U2(100) ; pad(4)] -> 208
static __device__ __forceinline__ _Float16 cw(const float* __restrict__ W,
                                              const float* __restrict__ U,
                                              int c, int k) {
    float v = (k < HH) ? W[k * G4 + c]
            : (k < 104 ? 0.0f : (k < 204 ? U[(k - 104) * G4 + c] : 0.0f));
    return (_Float16)v;
}

#define LWC(i) { const int k = kb + 2 * (i); \
  ca##i = h2{cw(W,U,cL,k), cw(W,U,cL,k+1)}; \
  cb##i = h2{cw(W,U,cH,k), cw(W,U,cH,k+1)}; }

// ---------------- dot kernels ----------------------------------------------
#define FD(w, x, acc) acc = __builtin_amdgcn_fdot2(w, x, acc, false)
#define B2(f) __builtin_bit_cast(h2, f)

// producer: one float4 chunk feeds 4 gates (8 chains via element parity)
#define DOTP(r, i0, i1, i2, i3) { const float4 v = vb[r]; \
  const h2 x0 = B2(v.x), x1 = B2(v.y), x2 = B2(v.z), x3 = B2(v.w); \
  FD(pa##i0, x0, zA0); FD(pb##i0, x0, zB0); FD(pc##i0, x0, zC0); FD(pd##i0, x0, zD0); \
  FD(pa##i1, x1, zA1); FD(pb##i1, x1, zB1); FD(pc##i1, x1, zC1); FD(pd##i1, x1, zD1); \
  FD(pa##i2, x2, zA0); FD(pb##i2, x2, zB0); FD(pc##i2, x2, zC0); FD(pd##i2, x2, zD0); \
  FD(pa##i3, x3, zA1); FD(pb##i3, x3, zB1); FD(pc##i3, x3, zC1); FD(pd##i3, x3, zD1); }

// consumer: one float4 chunk feeds 2 gates (4 chains via element parity)
#define DOTC(r, i0, i1, i2, i3) { const float4 v = vb[r]; \
  const h2 x0 = B2(v.x), x1 = B2(v.y), x2 = B2(v.z), x3 = B2(v.w); \
  FD(ca##i0, x0, zA0); FD(cb##i0, x0, zB0); \
  FD(ca##i1, x1, zA1); FD(cb##i1, x1, zB1); \
  FD(ca##i2, x2, zA0); FD(cb##i2, x2, zB0); \
  FD(ca##i3, x3, zA1); FD(cb##i3, x3, zB1); }

// consumer tail: halves [96,100) of the K-half (i = 48,49 real; 50,51 = pad)
#define DOTCT { const float2 v = *tb; \
  const h2 x0 = B2(v.x), x1 = B2(v.y); \
  FD(ca48, x0, zA0); FD(cb48, x0, zB0); \
  FD(ca49, x1, zA1); FD(cb49, x1, zB1); }

// ---------------- cross-lane primitives (DPP, pure VALU) --------------------
// 0xB1 = quad_perm [1,0,3,2] (xor 1), 0x4E = quad_perm [2,3,0,1] (xor 2)
static __device__ __forceinline__ float qsum4(float z) {
    int p1 = __builtin_amdgcn_update_dpp(0, __builtin_bit_cast(int, z),
                                         0xB1, 0xF, 0xF, true);
    float s1 = z + __builtin_bit_cast(float, p1);
    int p2 = __builtin_amdgcn_update_dpp(0, __builtin_bit_cast(int, s1),
                                         0x4E, 0xF, 0xF, true);
    return s1 + __builtin_bit_cast(float, p2);
}
static __device__ __forceinline__ float psum2(float z) {
    int p1 = __builtin_amdgcn_update_dpp(0, __builtin_bit_cast(int, z),
                                         0xB1, 0xF, 0xF, true);
    return z + __builtin_bit_cast(float, p1);
}
static __device__ __forceinline__ float xswap2(float z) {   // value from lane^2
    int p2 = __builtin_amdgcn_update_dpp(0, __builtin_bit_cast(int, z),
                                         0x4E, 0xF, 0xF, true);
    return __builtin_bit_cast(float, p2);
}
static __device__ __forceinline__ float sig(float z) {
    return 1.0f / (1.0f + __expf(-z));
}

__global__ __launch_bounds__(1024, 1)
void fused_lstm_kernel(const float* __restrict__ s,       // [B,T]
                       const float* __restrict__ conv_w,  // [2,1,F]
                       const float* __restrict__ conv_b,  // [F]
                       const float* __restrict__ w1, const float* __restrict__ u1,
                       const float* __restrict__ b1,
                       const float* __restrict__ w2, const float* __restrict__ u2,
                       const float* __restrict__ b2,
                       const float* __restrict__ dw, const float* __restrict__ db,
                       float* __restrict__ out)           // [B,3]
{
    const int tid = threadIdx.x;
    const int b   = blockIdx.x;

    __shared__ float s_buf[TT];                        // 8 KB input row
    __shared__ __align__(16) _Float16 X1[2 * K1];      // producer operand ring
    __shared__ __align__(16) _Float16 X2[2 * K2];      // consumer operand ring

    for (int i = tid; i < TT; i += 1024) s_buf[i] = s[(size_t)b * TT + i];
    if (tid < 2 * K1) X1[tid] = (_Float16)0.0f;        // pads stay 0 forever
    if (tid < 2 * K2) X2[tid] = (_Float16)0.0f;
    __syncthreads();                                   // (A)

    if (tid < 448) {
        // ============ PRODUCER: waves 0-6, 400 dot threads ============
        const int rt     = tid;
        const int active = (rt < 400);
        const int p      = active ? (rt >> 2) : 0;     // unit
        const int sq     = rt & 3;                     // K-quarter
        const int cA = p, cB = HH + p, cC = 2 * HH + p, cD = 3 * HH + p;
        const float* W = w1;
        const float* U = u1;
        const int kb = sq * 48;                        // quarter base (halves)

        L24(PDW)
        L24(LWP)
        const float bA = b1[cA], bB = b1[cB], bC = b1[cC], bD = b1[cD];
        __syncthreads();                               // (B)

        float c = 0.0f;
        for (int t = 0; t <= TP; ++t) {
            if (t < TP && active) {
                _Float16* cur = X1 + (t & 1) * K1;
                _Float16* nx1 = X1 + ((t & 1) ^ 1) * K1;
                _Float16* x2n = X2 + ((t & 1) ^ 1) * K2;
                float zA0 = 0.f, zA1 = 0.f, zB0 = 0.f, zB1 = 0.f;
                float zC0 = 0.f, zC1 = 0.f, zD0 = 0.f, zD1 = 0.f;
                const float4* vb = (const float4*)(cur + kb);
                DOTP(0, 0, 1, 2, 3)     DOTP(1, 4, 5, 6, 7)
                DOTP(2, 8, 9, 10, 11)   DOTP(3, 12, 13, 14, 15)
                DOTP(4, 16, 17, 18, 19) DOTP(5, 20, 21, 22, 23)
                const float zi = qsum4(zA0 + zA1) + bA;
                const float zf = qsum4(zB0 + zB1) + bB;
                const float zg = qsum4(zC0 + zC1) + bC;
                const float zo = qsum4(zD0 + zD1) + bD;
                c = fmaf(sig(zf), c, sig(zi) * fmaxf(zg, 0.f));
                const float h = sig(zo) * fmaxf(c, 0.f);
                if (sq == 0) {
                    const _Float16 hq = (_Float16)h;
                    nx1[FF + p] = hq;                  // h1 for LSTM1(t+1)
                    x2n[p]      = hq;                  // x2 for LSTM2
                }
            }
            __syncthreads();                           // (C)
        }
    } else if (tid < 896) {
        // ============ CONSUMER: waves 7-13, 400 dot threads ============
        const int rt     = tid - 448;
        const int active = (rt < 400);
        const int p      = active ? (rt >> 2) : 0;     // unit
        const int g2     = (rt >> 1) & 1;              // gate pair: 0->{i,f}, 1->{g,o}
        const int kh     = rt & 1;                     // K-half
        const int cL = (2 * g2) * HH + p;              // first gate col
        const int cH = cL + HH;                        // second gate col
        const float* W = w2;
        const float* U = u2;
        const int kb = kh * 104;                       // half base (halves)

        L50(CDW)
        L50(LWC)
        const float bL = b2[cL], bH = b2[cH];
        __syncthreads();                               // (B)

        float c = 0.0f;
        for (int t = 0; t <= TP; ++t) {
            if (t >= 1 && active) {                    // consumer step t-1
                _Float16* cur = X2 + (t & 1) * K2;
                float zA0 = 0.f, zA1 = 0.f, zB0 = 0.f, zB1 = 0.f;
                const float4* vb = (const float4*)(cur + kb);
                DOTC(0, 0, 1, 2, 3)      DOTC(1, 4, 5, 6, 7)
                DOTC(2, 8, 9, 10, 11)    DOTC(3, 12, 13, 14, 15)
                DOTC(4, 16, 17, 18, 19)  DOTC(5, 20, 21, 22, 23)
                DOTC(6, 24, 25, 26, 27)  DOTC(7, 28, 29, 30, 31)
                DOTC(8, 32, 33, 34, 35)  DOTC(9, 36, 37, 38, 39)
                DOTC(10, 40, 41, 42, 43) DOTC(11, 44, 45, 46, 47)
                const float2* tb = (const float2*)(cur + kb + 96);
                DOTCT
                // sum K-halves (partner = lane^1, same p,g2)
                const float za = psum2(zA0 + zA1) + bL;
                const float zb = psum2(zB0 + zB1) + bH;
                // exchange gate pairs (partner = lane^2, same p,kh)
                const float oa = xswap2(za);
                const float ob = xswap2(zb);
                const float zi = g2 ? oa : za;
                const float zf = g2 ? ob : zb;
                const float zg = g2 ? za : oa;
                const float zo = g2 ? zb : ob;
                c = fmaf(sig(zf), c, sig(zi) * fmaxf(zg, 0.f));
                const float h = sig(zo) * fmaxf(c, 0.f);
                if ((rt & 3) == 0)
                    X2[((t & 1) ^ 1) * K2 + 104 + p] = (_Float16)h;
            }
            __syncthreads();                           // (C)
        }

        // final h2(TP-1) was written at iter TP into slot ((TP&1)^1)=0
        if (rt == 0) {
            float l[3];
#pragma unroll
            for (int a = 0; a < 3; ++a) {
                float acc = db[a];
                for (int j = 0; j < HH; ++j)
                    acc = fmaf((float)X2[104 + j], dw[j * 3 + a], acc);
                l[a] = acc;
            }
            const float m = fmaxf(l[0], fmaxf(l[1], l[2]));
            const float e0 = __expf(l[0] - m), e1 = __expf(l[1] - m), e2 = __expf(l[2] - m);
            const float inv = 1.0f / (e0 + e1 + e2);
            out[b * 3 + 0] = e0 * inv;
            out[b * 3 + 1] = e1 * inv;
            out[b * 3 + 2] = e2 * inv;
        }
    } else if (tid < 960) {
        // ============ CONV: wave 14, 64 threads (1 filter each) ============
        const int f = tid - 896;
        const float cv0 = conv_w[f], cv1 = conv_w[FF + f], cb0 = conv_b[f];
        // x(0) into slot 0
        X1[f] = (_Float16)fmaxf(fmaf(s_buf[0], cv0, fmaf(s_buf[1], cv1, cb0)), 0.f);
        __syncthreads();                               // (B)

        for (int t = 0; t <= TP; ++t) {
            if (t + 1 < TP) {                          // conv x(t+1) into next slot
                _Float16* nx1 = X1 + ((t & 1) ^ 1) * K1;
                nx1[f] = (_Float16)fmaxf(fmaf(s_buf[t + 1], cv0, fmaf(s_buf[t + 2], cv1, cb0)), 0.f);
            }
            __syncthreads();                           // (C)
        }
    } else {
        // ============ wave 15: barrier companion only ============
        __syncthreads();                               // (B)
        for (int t = 0; t <= TP; ++t)
            __syncthreads();                           // (C)
    }
}

// ---------------- launch ----------------------------------------------------
extern "C" void kernel_launch(void* const* d_in, const int* in_sizes, int n_in,
                              void* d_out, int out_size, void* d_ws, size_t ws_size,
                              hipStream_t stream) {
    const float* s      = (const float*)d_in[0];
    const float* conv_w = (const float*)d_in[1];
    const float* conv_b = (const float*)d_in[2];
    const float* w1     = (const float*)d_in[3];
    const float* u1     = (const float*)d_in[4];
    const float* b1     = (const float*)d_in[5];
    const float* w2     = (const float*)d_in[6];
    const float* u2     = (const float*)d_in[7];
    const float* b2     = (const float*)d_in[8];
    const float* dw     = (const float*)d_in[9];
    const float* db     = (const float*)d_in[10];

    fused_lstm_kernel<<<BB, 1024, 0, stream>>>(
        s, conv_w, conv_b, w1, u1, b1, w2, u2, b2, dw, db, (float*)d_out);
}

// Round 6
// 2328.184 us; speedup vs baseline: 1.2808x; 1.2590x over previous
//
#include <hip/hip_runtime.h>
#include <math.h>

// Conv1D(k=2,F=64,relu) -> LSTM1(H=100, relu cell, seq) -> LSTM2 (last) ->
// Dense(3) -> softmax.  B=128, T=2048, T'=2047.
//
// Round-11 = round-10 with the name collision fixed (packed-weight pointers
// renamed gwp/gwc; 'wc4' collided with weight register wc##q for q=4).
//
//  * Register model (r8/r9): 1024-thr block forces 4 waves/SIMD = 128 total
//    regs/wave -> can never hold ~120 weight regs.  512-thr (512,2) = 2
//    waves/SIMD -> 256 regs/wave: the only shape that fits 176-200 h2
//    weights/thread.  r5 (2483us) was already in it.
//  * r5's residual overhead theory: the branchy f32 weight GATHER at init
//    (pw/cwf) spikes register pressure -> one-time scratch spill (15.7 MB
//    WRITE) that can anchor weights in scratch for the whole kernel
//    (L1-cached reloads invisible in HBM counters but costing issue slots
//    + waitcnts every step).
//  * Fix: PREP KERNEL packs all weights as f16 h2 pairs in exact per-thread
//    load order into d_ws; main kernel loads them with 44/50 streaming
//    global_load_dwordx4 into named regs.  No branches, no f32 temps.
//  * ds_swizzle pairsum -> DPP quad_perm xor-1 (psum2; proven r7-r9).
//  * Everything else is r5 verbatim: producer waves 0..3 (200 dot thr:
//    unit p = rt>>1, K-half odd = rt&1; 44 h2-pairs x 4 gates) + conv on
//    rt>=200; consumer waves 4..7 (200 dot thr: 50 h2-pairs x 4 gates);
//    2-slot LDS rings X1[2*176], X2[2*208]; 1 barrier/step.

typedef _Float16 h2 __attribute__((ext_vector_type(2)));

#define BB 128
#define TT 2048
#define TP 2047
#define HH 100
#define G4 400
#define FF 64

#define K1 176   // producer operand halves: [x(64) ; h1(100) ; pad(12)]
#define K2 208   // consumer operand halves: [x2(100); pad4 ; h2(100); pad4]

#define NPH2 (200 * 176)   // producer packed h2 count (200 thr x 44 pairs x 4 gates)
#define NCH2 (200 * 200)   // consumer packed h2 count (200 thr x 50 pairs x 4 gates)

#define L44(X) X(0) X(1) X(2) X(3) X(4) X(5) X(6) X(7) X(8) X(9) \
 X(10) X(11) X(12) X(13) X(14) X(15) X(16) X(17) X(18) X(19) \
 X(20) X(21) X(22) X(23) X(24) X(25) X(26) X(27) X(28) X(29) \
 X(30) X(31) X(32) X(33) X(34) X(35) X(36) X(37) X(38) X(39) \
 X(40) X(41) X(42) X(43)
#define L50(X) L44(X) X(44) X(45) X(46) X(47) X(48) X(49)

#define DW(q) h2 wa##q, wb##q, wc##q, wd##q;

// packed-weight loads: quad q = (pair q, gates 0..3), 16B contiguous
#define LWPK(q) { const float4 v = gwp[q]; \
  wa##q = B2(v.x); wb##q = B2(v.y); wc##q = B2(v.z); wd##q = B2(v.w); }
#define LWCK(q) { const float4 v = gwc[q]; \
  wa##q = B2(v.x); wb##q = B2(v.y); wc##q = B2(v.z); wd##q = B2(v.w); }

#define FD(w, x, acc) acc = __builtin_amdgcn_fdot2(w, x, acc, false)
#define B2(f) __builtin_bit_cast(h2, f)

#define DOT4(r, q0, q1, q2, q3) { const float4 v = vb[r]; \
  const h2 x0 = B2(v.x), x1 = B2(v.y), x2 = B2(v.z), x3 = B2(v.w); \
  FD(wa##q0, x0, zA0); FD(wb##q0, x0, zB0); FD(wc##q0, x0, zC0); FD(wd##q0, x0, zD0); \
  FD(wa##q1, x1, zA1); FD(wb##q1, x1, zB1); FD(wc##q1, x1, zC1); FD(wd##q1, x1, zD1); \
  FD(wa##q2, x2, zA0); FD(wb##q2, x2, zB0); FD(wc##q2, x2, zC0); FD(wd##q2, x2, zD0); \
  FD(wa##q3, x3, zA1); FD(wb##q3, x3, zB1); FD(wc##q3, x3, zC1); FD(wd##q3, x3, zD1); }

#define DOTT(q0, q1) { const float2 v = *tb; \
  const h2 x0 = B2(v.x), x1 = B2(v.y); \
  FD(wa##q0, x0, zA0); FD(wb##q0, x0, zB0); FD(wc##q0, x0, zC0); FD(wd##q0, x0, zD0); \
  FD(wa##q1, x1, zA1); FD(wb##q1, x1, zB1); FD(wc##q1, x1, zC1); FD(wd##q1, x1, zD1); }

// lane-pair sum via DPP quad_perm xor-1 (pure VALU; pairs never straddle a quad)
static __device__ __forceinline__ float psum2(float z) {
    int p1 = __builtin_amdgcn_update_dpp(0, __builtin_bit_cast(int, z),
                                         0xB1, 0xF, 0xF, true);
    return z + __builtin_bit_cast(float, p1);
}
static __device__ __forceinline__ float sig(float z) {
    return 1.0f / (1.0f + __expf(-z));
}

// ---------------- prep kernel: pack weights to f16 in per-thread order -----
// producer combined column: K = [conv-x(64) ; U1(100) ; pad(12)] -> 176
static __device__ __forceinline__ _Float16 pwv(const float* __restrict__ W,
                                               const float* __restrict__ U,
                                               int c, int k) {
    float v = (k < FF) ? W[k * G4 + c] : (k < FF + HH ? U[(k - FF) * G4 + c] : 0.0f);
    return (_Float16)v;
}
// consumer combined column: K = [W2(100) ; U2(100)] -> 200 (no pads in weights)
static __device__ __forceinline__ _Float16 cwv(const float* __restrict__ W,
                                               const float* __restrict__ U,
                                               int c, int k) {
    return (_Float16)((k < HH) ? W[k * G4 + c] : U[(k - HH) * G4 + c]);
}

__global__ void prep_weights(const float* __restrict__ w1, const float* __restrict__ u1,
                             const float* __restrict__ w2, const float* __restrict__ u2,
                             h2* __restrict__ ws)
{
    const int idx = blockIdx.x * 256 + threadIdx.x;   // h2 index
    if (idx >= NPH2 + NCH2) return;
    _Float16 lo, hi;
    if (idx < NPH2) {
        const int rt = idx / 176, r = idx % 176;
        const int i = r >> 2, g = r & 3;              // pair, gate
        const int p = rt >> 1, kb = (rt & 1) * 88;    // unit, K-half base
        const int c = g * HH + p;
        const int k = kb + 2 * i;
        lo = pwv(w1, u1, c, k); hi = pwv(w1, u1, c, k + 1);
    } else {
        const int j = idx - NPH2;
        const int rt = j / 200, r = j % 200;
        const int i = r >> 2, g = r & 3;
        const int p = rt >> 1, kw = (rt & 1) * 100;
        const int c = g * HH + p;
        const int k = kw + 2 * i;
        lo = cwv(w2, u2, c, k); hi = cwv(w2, u2, c, k + 1);
    }
    ws[idx] = h2{lo, hi};
}

// ---------------- main kernel ----------------------------------------------
__global__ __launch_bounds__(512, 2)
void fused_lstm_kernel(const float* __restrict__ s,       // [B,T]
                       const float* __restrict__ conv_w,  // [2,1,F]
                       const float* __restrict__ conv_b,  // [F]
                       const float* __restrict__ b1,
                       const float* __restrict__ b2,
                       const float* __restrict__ dw, const float* __restrict__ db,
                       const h2* __restrict__ wpk,        // packed weights
                       float* __restrict__ out)           // [B,3]
{
    const int tid = threadIdx.x;
    const int b   = blockIdx.x;

    __shared__ float s_buf[TT];                        // 8 KB input row
    __shared__ __align__(16) _Float16 X1[2 * K1];      // producer operand ring
    __shared__ __align__(16) _Float16 X2[2 * K2];      // consumer operand ring

    for (int i = tid; i < TT; i += 512) s_buf[i] = s[(size_t)b * TT + i];
    if (tid < 2 * K1) X1[tid] = (_Float16)0.0f;        // pads stay 0 forever
    if (tid < 2 * K2) X2[tid] = (_Float16)0.0f;
    __syncthreads();                                   // (A)

    if (tid < 256) {
        // ================= PRODUCER waves: conv + LSTM1 =================
        const int rt  = tid;
        const int p   = (rt < 200) ? (rt >> 1) : 0;
        const int odd = rt & 1;
        const int cA = p, cB = HH + p, cC = 2 * HH + p, cD = 3 * HH + p;
        const int kb = odd ? 88 : 0;                   // operand K-half base

        const float4* gwp = (const float4*)(wpk + (size_t)rt * 44 * 4);
        L44(DW)
        L44(LWPK)
        const float biA = b1[cA], biB = b1[cB], biC = b1[cC], biD = b1[cD];

        float cv0 = 0.f, cv1 = 0.f, cb0 = 0.f, cv0b = 0.f, cv1b = 0.f, cb0b = 0.f;
        const int f1 = rt - 200;
        if (rt >= 200) {
            cv0 = conv_w[f1]; cv1 = conv_w[FF + f1]; cb0 = conv_b[f1];
            if (f1 < 8) { cv0b = conv_w[56 + f1]; cv1b = conv_w[FF + 56 + f1]; cb0b = conv_b[56 + f1]; }
        }
        if (rt >= 200) {                               // x(0) into slot 0
            X1[f1] = (_Float16)fmaxf(fmaf(s_buf[0], cv0, fmaf(s_buf[1], cv1, cb0)), 0.f);
            if (f1 < 8)
                X1[56 + f1] = (_Float16)fmaxf(fmaf(s_buf[0], cv0b, fmaf(s_buf[1], cv1b, cb0b)), 0.f);
        }
        __syncthreads();                               // (B)

        float c = 0.0f;
        for (int t = 0; t <= TP; ++t) {
            if (t < TP) {
                _Float16* cur = X1 + (t & 1) * K1;
                _Float16* nx1 = X1 + ((t & 1) ^ 1) * K1;
                if (rt < 200) {
                    float zA0 = 0.f, zA1 = 0.f, zB0 = 0.f, zB1 = 0.f;
                    float zC0 = 0.f, zC1 = 0.f, zD0 = 0.f, zD1 = 0.f;
                    const float4* vb = (const float4*)(cur + kb);
                    DOT4(0,0,1,2,3)     DOT4(1,4,5,6,7)     DOT4(2,8,9,10,11)
                    DOT4(3,12,13,14,15) DOT4(4,16,17,18,19) DOT4(5,20,21,22,23)
                    DOT4(6,24,25,26,27) DOT4(7,28,29,30,31) DOT4(8,32,33,34,35)
                    DOT4(9,36,37,38,39) DOT4(10,40,41,42,43)
                    const float zi = psum2(zA0 + zA1) + biA;
                    const float zf = psum2(zB0 + zB1) + biB;
                    const float zg = psum2(zC0 + zC1) + biC;
                    const float zo = psum2(zD0 + zD1) + biD;
                    const float gi = sig(zi), gf = sig(zf), go = sig(zo);
                    const float gg = fmaxf(zg, 0.f);
                    c = fmaf(gf, c, gi * gg);
                    const float h = go * fmaxf(c, 0.f);
                    if (odd) {
                        const _Float16 hq = (_Float16)h;
                        nx1[FF + p] = hq;                          // h1 for LSTM1(t+1)
                        (X2 + ((t & 1) ^ 1) * K2)[p] = hq;         // x2 for LSTM2
                    }
                } else if (t + 1 < TP) {               // conv x(t+1) into next slot
                    nx1[f1] = (_Float16)fmaxf(fmaf(s_buf[t + 1], cv0, fmaf(s_buf[t + 2], cv1, cb0)), 0.f);
                    if (f1 < 8)
                        nx1[56 + f1] = (_Float16)fmaxf(fmaf(s_buf[t + 1], cv0b, fmaf(s_buf[t + 2], cv1b, cb0b)), 0.f);
                }
            }
            __syncthreads();                           // (C) one per step
        }
    } else {
        // ================= CONSUMER waves: LSTM2 + dense + softmax ==========
        const int rt  = tid - 256;
        const int p   = (rt < 200) ? (rt >> 1) : 0;
        const int odd = rt & 1;
        const int cA = p, cB = HH + p, cC = 2 * HH + p, cD = 3 * HH + p;
        const int kb = odd ? 104 : 0;                  // operand K-half base

        const float4* gwc = (const float4*)(wpk + NPH2 + (size_t)rt * 50 * 4);
        L50(DW)
        L50(LWCK)
        const float biA = b2[cA], biB = b2[cB], biC = b2[cC], biD = b2[cD];
        __syncthreads();                               // (B)

        float c = 0.0f;
        for (int t = 0; t <= TP; ++t) {
            if (t >= 1 && rt < 200) {                  // consumer step t-1
                _Float16* cur = X2 + (t & 1) * K2;
                float zA0 = 0.f, zA1 = 0.f, zB0 = 0.f, zB1 = 0.f;
                float zC0 = 0.f, zC1 = 0.f, zD0 = 0.f, zD1 = 0.f;
                const float4* vb = (const float4*)(cur + kb);
                DOT4(0,0,1,2,3)     DOT4(1,4,5,6,7)     DOT4(2,8,9,10,11)
                DOT4(3,12,13,14,15) DOT4(4,16,17,18,19) DOT4(5,20,21,22,23)
                DOT4(6,24,25,26,27) DOT4(7,28,29,30,31) DOT4(8,32,33,34,35)
                DOT4(9,36,37,38,39) DOT4(10,40,41,42,43) DOT4(11,44,45,46,47)
                const float2* tb = (const float2*)(cur + kb + 96);
                DOTT(48, 49)
                const float zi = psum2(zA0 + zA1) + biA;
                const float zf = psum2(zB0 + zB1) + biB;
                const float zg = psum2(zC0 + zC1) + biC;
                const float zo = psum2(zD0 + zD1) + biD;
                const float gi = sig(zi), gf = sig(zf), go = sig(zo);
                const float gg = fmaxf(zg, 0.f);
                c = fmaf(gf, c, gi * gg);
                const float h = go * fmaxf(c, 0.f);
                if (odd) X2[((t & 1) ^ 1) * K2 + 104 + p] = (_Float16)h;
            }
            __syncthreads();                           // (C) one per step
        }

        // final h2(TP-1) was written at iter TP into slot ((TP&1)^1)=0
        if (rt == 0) {
            float l[3];
#pragma unroll
            for (int a = 0; a < 3; ++a) {
                float acc = db[a];
                for (int j = 0; j < HH; ++j)
                    acc = fmaf((float)X2[104 + j], dw[j * 3 + a], acc);
                l[a] = acc;
            }
            const float m = fmaxf(l[0], fmaxf(l[1], l[2]));
            const float e0 = __expf(l[0] - m), e1 = __expf(l[1] - m), e2 = __expf(l[2] - m);
            const float inv = 1.0f / (e0 + e1 + e2);
            out[b * 3 + 0] = e0 * inv;
            out[b * 3 + 1] = e1 * inv;
            out[b * 3 + 2] = e2 * inv;
        }
    }
}

// ---------------- launch ----------------------------------------------------
extern "C" void kernel_launch(void* const* d_in, const int* in_sizes, int n_in,
                              void* d_out, int out_size, void* d_ws, size_t ws_size,
                              hipStream_t stream) {
    const float* s      = (const float*)d_in[0];
    const float* conv_w = (const float*)d_in[1];
    const float* conv_b = (const float*)d_in[2];
    const float* w1     = (const float*)d_in[3];
    const float* u1     = (const float*)d_in[4];
    const float* b1     = (const float*)d_in[5];
    const float* w2     = (const float*)d_in[6];
    const float* u2     = (const float*)d_in[7];
    const float* b2     = (const float*)d_in[8];
    const float* dw     = (const float*)d_in[9];
    const float* db     = (const float*)d_in[10];

    h2* ws = (h2*)d_ws;
    const int nh2 = NPH2 + NCH2;
    prep_weights<<<(nh2 + 255) / 256, 256, 0, stream>>>(w1, u1, w2, u2, ws);
    fused_lstm_kernel<<<BB, 512, 0, stream>>>(
        s, conv_w, conv_b, b1, b2, dw, db, ws, (float*)d_out);
}